// Round 18
// baseline (39.105 us; speedup 1.0000x reference)
//
#include <hip/hip_runtime.h>
#include <math.h>

// Problem constants
#define B_   2
#define L_   1024
#define M_   32
#define F_   256
#define C_   32
#define H_   12
#define QK_  16
#define HQK  192      // H*QK
#define KV2  384      // k+v cols (bf16 buffer row stride)
#define QKV3 576      // 3*HQK
#define FEAT 660      // H*C + H*QK + 7*H
#define FPAD 672      // FEAT padded to 21*32 for uniform MFMA K-loop
#define A2S  1360     // packed A tile stride (ushorts), 16B-aligned, spare 16
#define NTOK 2048     // B*L

constexpr float EPS_DIR     = 1e-4f;
constexpr float LN_EPS      = 1e-5f;
constexpr float BETA_COEF   = 0.23570226039551585f;  // sqrt(2/9)/2
constexpr float LOGIT_SCALE = 0.5773502691896258f;   // sqrt(1/3)

typedef __attribute__((ext_vector_type(8))) short  bf16x8;  // MFMA A/B frag
typedef __attribute__((ext_vector_type(4))) float  f32x4;   // MFMA C/D frag
typedef __attribute__((ext_vector_type(8))) ushort u16x8;   // 16B of bf16

static __device__ __forceinline__ ushort f2bf(float v) {
  union { float f; unsigned u; } x; x.f = v;
  unsigned r = x.u + 0x7FFFu + ((x.u >> 16) & 1u);   // RNE
  return (ushort)(r >> 16);
}
static __device__ __forceinline__ float bf2f(ushort h) {
  union { float f; unsigned u; } x; x.u = ((unsigned)h) << 16;
  return x.f;
}
static __device__ __forceinline__ void split4(const float* v,
                                              ushort4& h, ushort4& l) {
  h.x = f2bf(v[0]); l.x = f2bf(v[0] - bf2f(h.x));
  h.y = f2bf(v[1]); l.y = f2bf(v[1] - bf2f(h.y));
  h.z = f2bf(v[2]); l.z = f2bf(v[2] - bf2f(h.z));
  h.w = f2bf(v[3]); l.w = f2bf(v[3] - bf2f(h.w));
}
static __device__ __forceinline__ ushort4 pack4(const float* v) {
  ushort4 h;
  h.x = f2bf(v[0]); h.y = f2bf(v[1]);
  h.z = f2bf(v[2]); h.w = f2bf(v[3]);
  return h;
}
// Wave-level LDS fence: drain this wave's LDS ops + stop compiler reordering.
static __device__ __forceinline__ void wave_sync() {
  asm volatile("s_waitcnt lgkmcnt(0)" ::: "memory");
}

// ---------------------------------------------------------------------------
// K1': heterogeneous grid, 832 blocks x 256 thr (R14, proven).
//   0..511   : z gather -> dense BF16 z_d
//   512..543 : Wout -> hi-only TRANSPOSED wo, frag-permuted
//   544..831 : q = x@Wq (f32) ; k|v = x@[Wk|Wv] stored BF16
// ---------------------------------------------------------------------------
__global__ __launch_bounds__(256) void qkv_prep_kernel(
    const float* __restrict__ x,
    const float* __restrict__ Wq, const float* __restrict__ Wk,
    const float* __restrict__ Wv, const float* __restrict__ Wout,
    const float* __restrict__ z, const int* __restrict__ neighbors,
    float* __restrict__ qf, ushort* __restrict__ kvb,
    ushort* __restrict__ wo,
    ushort* __restrict__ z_d) {
  __shared__ ushort Ah[64][36], Al[64][36];   // [tok][k]
  __shared__ ushort Bh[64][36];               // [col][k] (transposed, hi only)
  const int bx  = blockIdx.x;
  const int tid = threadIdx.x;

  if (bx < 512) {                         // ---- z gather: 4 tokens/block ----
    const int t0 = bx * 4;
    for (int i = tid; i < 1024; i += 256) {
      int t = i >> 8, r = i & 255, m = r >> 3, cq = r & 7;
      int tok = t0 + t;
      int nb  = neighbors[tok * M_ + m];
      float4 v = *(const float4*)&z[((size_t)tok * L_ + nb) * C_ + cq * 4];
      *(ushort4*)&z_d[((size_t)tok * M_ + m) * C_ + cq * 4] =
          pack4((const float*)&v);
    }
    return;
  }
  if (bx < 544) {                         // ---- Wout transpose (hi only) ----
    const int base = (bx - 512) * 256 + tid;
#pragma unroll
    for (int rep = 0; rep < 6; ++rep) {
      int qid = base + rep * 8192;
      if (qid < 43008) {                  // 256 col x 168 k-quads
        int col = qid / 168;
        int k   = (qid - col * 168) * 4;
        float v[4];
#pragma unroll
        for (int j = 0; j < 4; ++j)
          v[j] = (k + j < FEAT) ? Wout[(size_t)(k + j) * F_ + col] : 0.f;
        ushort4 h4 = pack4(v);
        // frag-permuted offset: s*32 + half*4 + g*8
        int off = (k >> 5) * 32 + ((k & 16) >> 4) * 4 + ((k & 12) << 1);
        *(ushort4*)&wo[(size_t)col * FPAD + off] = h4;
      }
    }
    return;
  }

  // ---- MFMA part: tile (t0, c0), 64 tok x 64 col, K = 256 ----
  const int bxm = bx - 544;
  const int t0  = (bxm & 31) * 64;
  const int c0  = (bxm >> 5) * 64;
  const int w   = tid >> 6;
  const int l   = tid & 63;
  const int lr  = l & 15;
  const int lk  = (l >> 4) * 4;

  const float* Wb   = (c0 < HQK) ? Wq : (c0 < 2 * HQK) ? Wk : Wv;
  const int    cOff = (c0 < HQK) ? c0 : (c0 < 2 * HQK) ? c0 - HQK
                                                       : c0 - 2 * HQK;

  union ABFrag { bf16x8 v; ushort4 h[2]; };

  const int arow0 = tid >> 3,  akc0 = (tid & 7) * 4;
  const int arow1 = (tid + 256) >> 3, akc1 = ((tid + 256) & 7) * 4;
  const int bk0 = tid >> 4,  bcc0 = (tid & 15) * 4;
  const int bk1 = (tid + 256) >> 4, bcc1 = ((tid + 256) & 15) * 4;

  f32x4 acc[4];
#pragma unroll
  for (int n = 0; n < 4; ++n) acc[n] = (f32x4){0.f, 0.f, 0.f, 0.f};

  float4 xr0 = *(const float4*)&x[(size_t)(t0 + arow0) * F_ + akc0];
  float4 xr1 = *(const float4*)&x[(size_t)(t0 + arow1) * F_ + akc1];
  float4 wr0 = *(const float4*)&Wb[(size_t)bk0 * HQK + cOff + bcc0];
  float4 wr1 = *(const float4*)&Wb[(size_t)bk1 * HQK + cOff + bcc1];

  for (int s = 0; s < 8; ++s) {
    __syncthreads();                      // prev MFMAs done reading LDS
    {
      ushort4 h4, l4;
      split4((const float*)&xr0, h4, l4);
      *(ushort4*)&Ah[arow0][akc0] = h4;
      *(ushort4*)&Al[arow0][akc0] = l4;
      split4((const float*)&xr1, h4, l4);
      *(ushort4*)&Ah[arow1][akc1] = h4;
      *(ushort4*)&Al[arow1][akc1] = l4;
      ushort4 b0 = pack4((const float*)&wr0);
      Bh[bcc0 + 0][bk0] = b0.x;  Bh[bcc0 + 1][bk0] = b0.y;
      Bh[bcc0 + 2][bk0] = b0.z;  Bh[bcc0 + 3][bk0] = b0.w;
      ushort4 b1 = pack4((const float*)&wr1);
      Bh[bcc1 + 0][bk1] = b1.x;  Bh[bcc1 + 1][bk1] = b1.y;
      Bh[bcc1 + 2][bk1] = b1.z;  Bh[bcc1 + 3][bk1] = b1.w;
    }
    __syncthreads();

    if (s < 7) {                          // T14: issue next-step loads early
      int sn = (s + 1) * 32;
      xr0 = *(const float4*)&x[(size_t)(t0 + arow0) * F_ + sn + akc0];
      xr1 = *(const float4*)&x[(size_t)(t0 + arow1) * F_ + sn + akc1];
      wr0 = *(const float4*)&Wb[(size_t)(sn + bk0) * HQK + cOff + bcc0];
      wr1 = *(const float4*)&Wb[(size_t)(sn + bk1) * HQK + cOff + bcc1];
    }

    ABFrag a_h, a_l;
    a_h.h[0] = *(const ushort4*)&Ah[w * 16 + lr][lk];
    a_h.h[1] = *(const ushort4*)&Ah[w * 16 + lr][16 + lk];
    a_l.h[0] = *(const ushort4*)&Al[w * 16 + lr][lk];
    a_l.h[1] = *(const ushort4*)&Al[w * 16 + lr][16 + lk];
#pragma unroll
    for (int n = 0; n < 4; ++n) {
      ABFrag b_h;
      b_h.h[0] = *(const ushort4*)&Bh[n * 16 + lr][lk];
      b_h.h[1] = *(const ushort4*)&Bh[n * 16 + lr][16 + lk];
      acc[n] = __builtin_amdgcn_mfma_f32_16x16x32_bf16(a_h.v, b_h.v, acc[n], 0, 0, 0);
      acc[n] = __builtin_amdgcn_mfma_f32_16x16x32_bf16(a_l.v, b_h.v, acc[n], 0, 0, 0);
    }
  }

  if (c0 < HQK) {                         // q region -> f32
#pragma unroll
    for (int n = 0; n < 4; ++n)
#pragma unroll
      for (int i = 0; i < 4; ++i)
        qf[(size_t)(t0 + w * 16 + lk + i) * HQK + c0 + n * 16 + lr] =
            acc[n][i];
  } else {                                // k|v region -> bf16
    const int cb0 = c0 - HQK;
#pragma unroll
    for (int n = 0; n < 4; ++n)
#pragma unroll
      for (int i = 0; i < 4; ++i)
        kvb[(size_t)(t0 + w * 16 + lk + i) * KV2 + cb0 + n * 16 + lr] =
            f2bf(acc[n][i]);
  }
}

// ---------------------------------------------------------------------------
// K2+K3 fused (R14 structure). NEW: T14 on the logits k-rows -- each lane
// reads its neighbor index from GLOBAL at kernel entry and issues its 12
// contiguous u16x8 k-loads into registers BEFORE the staging phase; the
// scattered L2 latency drains under staging + barrier instead of sitting on
// the logits critical path. Pair-term and all numerics bit-identical.
// ---------------------------------------------------------------------------
__global__ __launch_bounds__(512) void attn_out_kernel(
    const float* __restrict__ R, const float* __restrict__ tvec,
    const float* __restrict__ pCB, const ushort* __restrict__ z_d,
    const int*   __restrict__ neighbors,
    const float* __restrict__ Wpair, const float* __restrict__ spatial_coef,
    const float* __restrict__ qf, const ushort* __restrict__ kvb,
    const ushort* __restrict__ wo,
    const float* __restrict__ b_out, const float* __restrict__ x,
    const float* __restrict__ ln_g, const float* __restrict__ ln_b,
    float* __restrict__ out) {
  const int tid   = threadIdx.x;          // 0..511
  const int t0    = blockIdx.x * 8;
  const int bbase = t0 & ~(L_ - 1);
  const int wv    = tid >> 6;             // wave id == token index t
  const int l     = tid & 63;

  __shared__ float  q_s[8][HQK];
  __shared__ ushort z_s[8][M_][36];       // bf16 z tile (18.4 KB)
  __shared__ float  alpha_s[8][M_][13];
  __shared__ float  p_s[8][M_][4];
  __shared__ float  wp_s[C_ * H_];
  __shared__ float  gam_s[H_];
  __shared__ float  geo_s[8][16];
  __shared__ int    nb_s[8][M_];
  __shared__ float  aggr_s[8][H_][4];
  __shared__ ushort A2[8][A2S];           // packed feat {h4,l4}, 21.8 KB
  __shared__ float  part[16][8][2];
  __shared__ float  mu_s[16], rs_s[16];

  union U8 { u16x8 v; ushort e[8]; };

  // ---- T14: issue this lane's logits k-row loads FIRST (12 x 16B,
  // contiguous 96 ushorts at head-group base). Latency hides under staging.
  const int m_pre  = l & 31;
  const int hb_pre = (l >> 5) * 6;
  const int nb_pre = neighbors[(t0 + wv) * M_ + m_pre];
  U8 kpre[12];
  {
    const ushort* kr =
        kvb + (size_t)(bbase + nb_pre) * KV2 + hb_pre * QK_;
#pragma unroll
    for (int j = 0; j < 12; ++j)
      kpre[j].v = *(const u16x8*)&kr[j * 8];
  }

  // ---- staging (cross-wave, barrier after) ----
  if (tid < 256) {
    int t = tid >> 5, m = tid & 31;
    nb_s[t][m] = neighbors[(t0 + t) * M_ + m];
  } else if (tid - 256 < H_) {
    gam_s[tid - 256] = log1pf(expf(spatial_coef[tid - 256]));
  }
  if (tid < C_ * H_) wp_s[tid] = Wpair[tid];
  if (tid < 96) {                         // zero 12 pad cols per token
    int t = tid / 12, c = FEAT + tid % 12;
    A2[t][(c >> 2) * 8 + (c & 3)]     = 0;
    A2[t][(c >> 2) * 8 + (c & 3) + 4] = 0;
  }
  if (tid < 384) {
    int t = tid / 48, r = tid % 48;
    *(float4*)&q_s[t][r * 4] =
        *(const float4*)&qf[(size_t)(t0 + t) * HQK + r * 4];
  }
  if (tid >= 384 && tid < 504) {
    int j = tid - 384, t = j / 15, w = j % 15;
    geo_s[t][w] = (w < 3) ? pCB[(t0 + t) * 3 + w]
                : (w < 6) ? tvec[(t0 + t) * 3 + (w - 3)]
                          : R[(t0 + t) * 9 + (w - 6)];
  }
  for (int i = tid; i < 2048; i += 512) {
    int t = i >> 8, r = i & 255, m = r >> 3, cq = r & 7;
    ushort4 v = *(const ushort4*)&z_d[((size_t)(t0 + t) * M_ + m) * C_ + cq * 4];
    *(ushort4*)&z_s[t][m][cq * 4] = v;
  }
  for (int i = tid; i < 8 * M_ * 3; i += 512) {
    int t = i / 96, r = i % 96, m = r / 3, ii = r % 3;
    int nb = neighbors[(t0 + t) * M_ + m];
    p_s[t][m][ii] = pCB[(bbase + nb) * 3 + ii];
  }
  __syncthreads();

  // ---- logits + softmax (wave-local; lane = (hgrp, m)) ----
  {
    const int t  = wv;
    const int m  = l & 31;
    const int hb = (l >> 5) * 6;         // head base: 0 or 6
    float lg[6];
#pragma unroll
    for (int h = 0; h < 6; ++h) lg[h] = 0.f;
#pragma unroll
    for (int c = 0; c < C_; ++c) {
      float zv = bf2f(z_s[t][m][c]);
#pragma unroll
      for (int h = 0; h < 6; ++h) lg[h] += zv * wp_s[c * H_ + hb + h];
    }
#pragma unroll
    for (int h = 0; h < 6; ++h) {
      const int hh = hb + h;
      U8 ka = kpre[h * 2], kb2 = kpre[h * 2 + 1];   // prefetched k-row
      const float4* q4 = (const float4*)&q_s[t][hh * 16];
      float4 qa = q4[0], qb = q4[1], qc = q4[2], qd = q4[3];
      float nd = bf2f(ka.e[0]) * qa.x + bf2f(ka.e[1]) * qa.y
               + bf2f(ka.e[2]) * qa.z + bf2f(ka.e[3]) * qa.w
               + bf2f(ka.e[4]) * qb.x + bf2f(ka.e[5]) * qb.y
               + bf2f(ka.e[6]) * qb.z + bf2f(ka.e[7]) * qb.w
               + bf2f(kb2.e[0]) * qc.x + bf2f(kb2.e[1]) * qc.y
               + bf2f(kb2.e[2]) * qc.z + bf2f(kb2.e[3]) * qc.w
               + bf2f(kb2.e[4]) * qd.x + bf2f(kb2.e[5]) * qd.y
               + bf2f(kb2.e[6]) * qd.z + bf2f(kb2.e[7]) * qd.w;
      lg[h] += nd;
    }
    float dx = geo_s[t][0] - p_s[t][m][0];
    float dy = geo_s[t][1] - p_s[t][m][1];
    float dz = geo_s[t][2] - p_s[t][m][2];
    float d2 = dx * dx + dy * dy + dz * dz;
#pragma unroll
    for (int h = 0; h < 6; ++h)
      lg[h] = (lg[h] - d2 * gam_s[hb + h] * BETA_COEF) * LOGIT_SCALE;
#pragma unroll
    for (int h = 0; h < 6; ++h) {
      float mx = lg[h];
#pragma unroll
      for (int o = 16; o; o >>= 1) mx = fmaxf(mx, __shfl_xor(mx, o));
      float p = expf(lg[h] - mx);
      float s = p;
#pragma unroll
      for (int o = 16; o; o >>= 1) s += __shfl_xor(s, o);
      alpha_s[t][m][hb + h] = p / s;
    }
  }
  wave_sync();                            // alpha visible within wave

  // ---- feat_p2n -> A2 cols [0,384) (wave-local; z read ushort4) ----
  {
    const int t = wv;
    const int hp = l >> 3, cq = l & 7;
    if (hp < 6) {
      float acc0[4] = {0, 0, 0, 0}, acc1[4] = {0, 0, 0, 0};
#pragma unroll
      for (int m = 0; m < M_; ++m) {
        float a0 = alpha_s[t][m][hp * 2];
        float a1 = alpha_s[t][m][hp * 2 + 1];
        ushort4 zz = *(const ushort4*)&z_s[t][m][cq * 4];
        float z0 = bf2f(zz.x), z1 = bf2f(zz.y);
        float z2 = bf2f(zz.z), z3 = bf2f(zz.w);
        acc0[0] += a0 * z0; acc0[1] += a0 * z1;
        acc0[2] += a0 * z2; acc0[3] += a0 * z3;
        acc1[0] += a1 * z0; acc1[1] += a1 * z1;
        acc1[2] += a1 * z2; acc1[3] += a1 * z3;
      }
      ushort4 h4, l4;
      int c = (hp * 2) * C_ + cq * 4;
      split4(acc0, h4, l4);
      *(ushort4*)&A2[t][c * 2]     = h4;
      *(ushort4*)&A2[t][c * 2 + 4] = l4;
      c = (hp * 2 + 1) * C_ + cq * 4;
      split4(acc1, h4, l4);
      *(ushort4*)&A2[t][c * 2]     = h4;
      *(ushort4*)&A2[t][c * 2 + 4] = l4;
    }
  }
  // ---- feat_node -> A2 cols [384,576) (wave-local; v read bf16) ----
  {
    const int t = wv;
    const int h = l >> 2, dq = l & 3;
    if (h < 12) {
      float acc[4] = {0, 0, 0, 0};
#pragma unroll
      for (int m = 0; m < M_; ++m) {
        float a = alpha_s[t][m][h];
        const ushort* vr = kvb + (size_t)(bbase + nb_s[t][m]) * KV2 + HQK;
        ushort4 v4 = *(const ushort4*)&vr[h * QK_ + dq * 4];
        acc[0] += a * bf2f(v4.x); acc[1] += a * bf2f(v4.y);
        acc[2] += a * bf2f(v4.z); acc[3] += a * bf2f(v4.w);
      }
      ushort4 h4, l4;
      split4(acc, h4, l4);
      int c = 384 + h * QK_ + dq * 4;
      *(ushort4*)&A2[t][c * 2]     = h4;
      *(ushort4*)&A2[t][c * 2 + 4] = l4;
    }
  }
  // ---- aggr (wave-local: lanes 0..35) ----
  if (l < 36) {
    const int t = wv;
    int h = l / 3, ii = l % 3;
    float f = 0.f;
#pragma unroll
    for (int m = 0; m < M_; ++m) f += alpha_s[t][m][h] * p_s[t][m][ii];
    aggr_s[t][h][ii] = f;
  }
  wave_sync();                            // aggr visible within wave

  // ---- spatial feats -> A2 cols [576,660) (wave-local: lanes 0..11) ----
  if (l < 12) {
    const int t = wv;
    const int h = l;
    float a0 = aggr_s[t][h][0] - geo_s[t][3];
    float a1 = aggr_s[t][h][1] - geo_s[t][4];
    float a2 = aggr_s[t][h][2] - geo_s[t][5];
    float lx = geo_s[t][6] * a0 + geo_s[t][9]  * a1 + geo_s[t][12] * a2;
    float ly = geo_s[t][7] * a0 + geo_s[t][10] * a1 + geo_s[t][13] * a2;
    float lz = geo_s[t][8] * a0 + geo_s[t][11] * a1 + geo_s[t][14] * a2;
    float dist = sqrtf(lx * lx + ly * ly + lz * lz);
    float inv  = 1.f / (dist + EPS_DIR);
    float vals[7] = {lx, ly, lz, dist, lx * inv, ly * inv, lz * inv};
    int   cols[7] = {576 + 3 * h, 577 + 3 * h, 578 + 3 * h, 612 + h,
                     624 + 3 * h, 625 + 3 * h, 626 + 3 * h};
#pragma unroll
    for (int j = 0; j < 7; ++j) {
      int c = cols[j];
      ushort hh = f2bf(vals[j]);
      A2[t][(c >> 2) * 8 + (c & 3)]     = hh;
      A2[t][(c >> 2) * 8 + (c & 3) + 4] = f2bf(vals[j] - bf2f(hh));
    }
  }

  // ---- out GEMM: 8 tok (dual-row hi/lo) x 256 col, K = 672, hi-only B ----
  const int w  = wv;
  const int lr = l & 15, lk = (l >> 4) * 4;
  const int atok = lr & 7;                // A row -> token
  const int asel = (lr >> 3) * 4;         // 0 = hi quad, 4 = lo quad
  const int col0 = (w * 2 + 0) * 16 + lr;
  const int col1 = (w * 2 + 1) * 16 + lr;
  // frag-permuted wo: lane's 16B at col*FPAD + s*32 + lk*2 holds
  // {k=s*32+lk..+3, k=s*32+16+lk..+3} -- exactly h[0],h[1].
  const ushort* wo0 = wo + (size_t)col0 * FPAD + lk * 2;
  const ushort* wo1 = wo + (size_t)col1 * FPAD + lk * 2;

  union ABFrag { bf16x8 v; ushort4 h[2]; };
  union B8 { u16x8 v; ushort4 q[2]; };

  B8 pb[4][2];                            // [buf][n] depth-4 ring

#define PREF_B(sstep, buf) do {                                          \
    pb[buf][0].v = *(const u16x8*)&wo0[(sstep) * 32];                    \
    pb[buf][1].v = *(const u16x8*)&wo1[(sstep) * 32];                    \
  } while (0)

  PREF_B(0, 0);                           // overlap with spatial phase +
  PREF_B(1, 1);                           // the barrier below
  PREF_B(2, 2);
  PREF_B(3, 3);
  __syncthreads();                        // feat LDS ready (cross-wave)

  f32x4 acc[2];
  acc[0] = (f32x4){0.f, 0.f, 0.f, 0.f};
  acc[1] = (f32x4){0.f, 0.f, 0.f, 0.f};

#pragma unroll
  for (int s = 0; s < 21; ++s) {
    const int cb = s & 3;
    // A frag, proven k-split: k = {s*32+lk..+3} u {s*32+16+lk..+3};
    // asel picks hi (rows 0..7) or lo (rows 8..15) quad of the packed pair.
    const int k0 = s * 32 + lk;
    ABFrag a;
    a.h[0] = *(const ushort4*)&A2[atok][k0 * 2 + asel];
    a.h[1] = *(const ushort4*)&A2[atok][(k0 + 16) * 2 + asel];
    ABFrag b0, b1;
    b0.h[0] = pb[cb][0].q[0];  b0.h[1] = pb[cb][0].q[1];
    b1.h[0] = pb[cb][1].q[0];  b1.h[1] = pb[cb][1].q[1];
    if (s < 17) PREF_B(s + 4, cb);        // refill consumed ring slot
    acc[0] = __builtin_amdgcn_mfma_f32_16x16x32_bf16(a.v, b0.v, acc[0], 0, 0, 0);
    acc[1] = __builtin_amdgcn_mfma_f32_16x16x32_bf16(a.v, b1.v, acc[1], 0, 0, 0);
  }
#undef PREF_B

  // cross-half combine: C row r (r<8) = acc[r] + acc[r+8] = (hi+lo)*bh;
  // l^32 flips the C row by 8 (col = l&15 preserved); both halves identical.
#pragma unroll
  for (int n = 0; n < 2; ++n)
#pragma unroll
    for (int i = 0; i < 4; ++i)
      acc[n][i] += __shfl_xor(acc[n][i], 32);

  // ---- epilogue: h = acc + b_out + x; block-local LN over 256 cols ----
  float hv[4][2];                          // [row i][col tile n]
#pragma unroll
  for (int i = 0; i < 4; ++i) {
    const int row = (lk + i) & 7;          // rows 8..15 duplicate 0..7
#pragma unroll
    for (int n = 0; n < 2; ++n) {
      const int col = (w * 2 + n) * 16 + lr;
      hv[i][n] = acc[n][i] + b_out[col] + x[(size_t)(t0 + row) * F_ + col];
    }
  }
#pragma unroll
  for (int i = 0; i < 4; ++i) {
    float s  = hv[i][0] + hv[i][1];
    float sq = hv[i][0] * hv[i][0] + hv[i][1] * hv[i][1];
#pragma unroll
    for (int o = 1; o < 16; o <<= 1) {     // reduce within 16-lane group
      s  += __shfl_xor(s, o);
      sq += __shfl_xor(sq, o);
    }
    if (lr == 0) {
      part[lk + i][w][0] = s;              // raw row index: unique writer
      part[lk + i][w][1] = sq;
    }
  }
  __syncthreads();
  if (tid < 16) {
    float s = 0.f, sq = 0.f;
#pragma unroll
    for (int ww = 0; ww < 8; ++ww) {
      s  += part[tid][ww][0];
      sq += part[tid][ww][1];
    }
    float mu = s * (1.f / F_);
    mu_s[tid] = mu;
    rs_s[tid] = rsqrtf(sq * (1.f / F_) - mu * mu + LN_EPS);
  }
  __syncthreads();

  if (lk < 8) {                            // rows 0..7 only (8..15 dup)
#pragma unroll
    for (int n = 0; n < 2; ++n) {
      const int col = (w * 2 + n) * 16 + lr;
      const float g = ln_g[col], be = ln_b[col];
#pragma unroll
      for (int i = 0; i < 4; ++i) {
        const int row = lk + i;
        out[(size_t)(t0 + row) * F_ + col] =
            (hv[i][n] - mu_s[row]) * rs_s[row] * g + be;
      }
    }
  }
}

// ---------------------------------------------------------------------------
extern "C" void kernel_launch(void* const* d_in, const int* in_sizes, int n_in,
                              void* d_out, int out_size, void* d_ws,
                              size_t ws_size, hipStream_t stream) {
  const float* R     = (const float*)d_in[0];
  const float* t     = (const float*)d_in[1];
  const float* pCB   = (const float*)d_in[2];
  const float* x     = (const float*)d_in[3];
  const float* z     = (const float*)d_in[4];
  const int*   nb    = (const int*)d_in[6];
  const float* Wq    = (const float*)d_in[7];
  const float* Wk    = (const float*)d_in[8];
  const float* Wv    = (const float*)d_in[9];
  const float* Wpair = (const float*)d_in[10];
  const float* sc    = (const float*)d_in[11];
  const float* Wout  = (const float*)d_in[12];
  const float* bout  = (const float*)d_in[13];
  const float* g     = (const float*)d_in[14];
  const float* be    = (const float*)d_in[15];
  float* out  = (float*)d_out;

  float*  qf   = (float*)d_ws;                     // 2048*192 f32
  ushort* kvb  = (ushort*)(qf + (size_t)NTOK * HQK);   // 2048*384 bf16
  ushort* z_d  = kvb + (size_t)NTOK * KV2;             // 2048*32*32 bf16
  ushort* wo   = z_d + (size_t)NTOK * M_ * C_;         // 256*672 hi-only

  qkv_prep_kernel<<<832, 256, 0, stream>>>(x, Wq, Wk, Wv, Wout, z, nb,
                                           qf, kvb, wo, z_d);
  attn_out_kernel<<<NTOK / 8, 512, 0, stream>>>(R, t, pCB, z_d, nb, Wpair,
                                                sc, qf, kvb, wo, bout, x,
                                                g, be, out);
}

// Round 19
// 37.364 us; speedup vs baseline: 1.0466x; 1.0466x over previous
//
#include <hip/hip_runtime.h>
#include <math.h>

// Problem constants
#define B_   2
#define L_   1024
#define M_   32
#define F_   256
#define C_   32
#define H_   12
#define QK_  16
#define HQK  192      // H*QK
#define KV2  384      // k+v cols (bf16 buffer row stride)
#define QKV3 576      // 3*HQK
#define FEAT 660      // H*C + H*QK + 7*H
#define FPAD 672      // FEAT padded to 21*32 for uniform MFMA K-loop
#define A2S  1360     // packed A tile stride (ushorts), 16B-aligned, spare 16
#define NTOK 2048     // B*L

constexpr float EPS_DIR     = 1e-4f;
constexpr float LN_EPS      = 1e-5f;
constexpr float BETA_COEF   = 0.23570226039551585f;  // sqrt(2/9)/2
constexpr float LOGIT_SCALE = 0.5773502691896258f;   // sqrt(1/3)

typedef __attribute__((ext_vector_type(8))) short  bf16x8;  // MFMA A/B frag
typedef __attribute__((ext_vector_type(4))) float  f32x4;   // MFMA C/D frag
typedef __attribute__((ext_vector_type(8))) ushort u16x8;   // 16B of bf16

static __device__ __forceinline__ ushort f2bf(float v) {
  union { float f; unsigned u; } x; x.f = v;
  unsigned r = x.u + 0x7FFFu + ((x.u >> 16) & 1u);   // RNE
  return (ushort)(r >> 16);
}
static __device__ __forceinline__ float bf2f(ushort h) {
  union { float f; unsigned u; } x; x.u = ((unsigned)h) << 16;
  return x.f;
}
static __device__ __forceinline__ void split4(const float* v,
                                              ushort4& h, ushort4& l) {
  h.x = f2bf(v[0]); l.x = f2bf(v[0] - bf2f(h.x));
  h.y = f2bf(v[1]); l.y = f2bf(v[1] - bf2f(h.y));
  h.z = f2bf(v[2]); l.z = f2bf(v[2] - bf2f(h.z));
  h.w = f2bf(v[3]); l.w = f2bf(v[3] - bf2f(h.w));
}
static __device__ __forceinline__ ushort4 pack4(const float* v) {
  ushort4 h;
  h.x = f2bf(v[0]); h.y = f2bf(v[1]);
  h.z = f2bf(v[2]); h.w = f2bf(v[3]);
  return h;
}
// Wave-level LDS fence: drain this wave's LDS ops + stop compiler reordering.
static __device__ __forceinline__ void wave_sync() {
  asm volatile("s_waitcnt lgkmcnt(0)" ::: "memory");
}

// ---------------------------------------------------------------------------
// K1': heterogeneous grid, 832 blocks x 256 thr (R14, proven).
//   0..511   : z gather -> dense BF16 z_d
//   512..543 : Wout -> hi-only TRANSPOSED wo, frag-permuted
//   544..831 : q = x@Wq (f32) ; k|v = x@[Wk|Wv] stored BF16
// ---------------------------------------------------------------------------
__global__ __launch_bounds__(256) void qkv_prep_kernel(
    const float* __restrict__ x,
    const float* __restrict__ Wq, const float* __restrict__ Wk,
    const float* __restrict__ Wv, const float* __restrict__ Wout,
    const float* __restrict__ z, const int* __restrict__ neighbors,
    float* __restrict__ qf, ushort* __restrict__ kvb,
    ushort* __restrict__ wo,
    ushort* __restrict__ z_d) {
  __shared__ ushort Ah[64][36], Al[64][36];   // [tok][k]
  __shared__ ushort Bh[64][36];               // [col][k] (transposed, hi only)
  const int bx  = blockIdx.x;
  const int tid = threadIdx.x;

  if (bx < 512) {                         // ---- z gather: 4 tokens/block ----
    const int t0 = bx * 4;
    for (int i = tid; i < 1024; i += 256) {
      int t = i >> 8, r = i & 255, m = r >> 3, cq = r & 7;
      int tok = t0 + t;
      int nb  = neighbors[tok * M_ + m];
      float4 v = *(const float4*)&z[((size_t)tok * L_ + nb) * C_ + cq * 4];
      *(ushort4*)&z_d[((size_t)tok * M_ + m) * C_ + cq * 4] =
          pack4((const float*)&v);
    }
    return;
  }
  if (bx < 544) {                         // ---- Wout transpose (hi only) ----
    const int base = (bx - 512) * 256 + tid;
#pragma unroll
    for (int rep = 0; rep < 6; ++rep) {
      int qid = base + rep * 8192;
      if (qid < 43008) {                  // 256 col x 168 k-quads
        int col = qid / 168;
        int k   = (qid - col * 168) * 4;
        float v[4];
#pragma unroll
        for (int j = 0; j < 4; ++j)
          v[j] = (k + j < FEAT) ? Wout[(size_t)(k + j) * F_ + col] : 0.f;
        ushort4 h4 = pack4(v);
        // frag-permuted offset: s*32 + half*4 + g*8
        int off = (k >> 5) * 32 + ((k & 16) >> 4) * 4 + ((k & 12) << 1);
        *(ushort4*)&wo[(size_t)col * FPAD + off] = h4;
      }
    }
    return;
  }

  // ---- MFMA part: tile (t0, c0), 64 tok x 64 col, K = 256 ----
  const int bxm = bx - 544;
  const int t0  = (bxm & 31) * 64;
  const int c0  = (bxm >> 5) * 64;
  const int w   = tid >> 6;
  const int l   = tid & 63;
  const int lr  = l & 15;
  const int lk  = (l >> 4) * 4;

  const float* Wb   = (c0 < HQK) ? Wq : (c0 < 2 * HQK) ? Wk : Wv;
  const int    cOff = (c0 < HQK) ? c0 : (c0 < 2 * HQK) ? c0 - HQK
                                                       : c0 - 2 * HQK;

  union ABFrag { bf16x8 v; ushort4 h[2]; };

  const int arow0 = tid >> 3,  akc0 = (tid & 7) * 4;
  const int arow1 = (tid + 256) >> 3, akc1 = ((tid + 256) & 7) * 4;
  const int bk0 = tid >> 4,  bcc0 = (tid & 15) * 4;
  const int bk1 = (tid + 256) >> 4, bcc1 = ((tid + 256) & 15) * 4;

  f32x4 acc[4];
#pragma unroll
  for (int n = 0; n < 4; ++n) acc[n] = (f32x4){0.f, 0.f, 0.f, 0.f};

  float4 xr0 = *(const float4*)&x[(size_t)(t0 + arow0) * F_ + akc0];
  float4 xr1 = *(const float4*)&x[(size_t)(t0 + arow1) * F_ + akc1];
  float4 wr0 = *(const float4*)&Wb[(size_t)bk0 * HQK + cOff + bcc0];
  float4 wr1 = *(const float4*)&Wb[(size_t)bk1 * HQK + cOff + bcc1];

  for (int s = 0; s < 8; ++s) {
    __syncthreads();                      // prev MFMAs done reading LDS
    {
      ushort4 h4, l4;
      split4((const float*)&xr0, h4, l4);
      *(ushort4*)&Ah[arow0][akc0] = h4;
      *(ushort4*)&Al[arow0][akc0] = l4;
      split4((const float*)&xr1, h4, l4);
      *(ushort4*)&Ah[arow1][akc1] = h4;
      *(ushort4*)&Al[arow1][akc1] = l4;
      ushort4 b0 = pack4((const float*)&wr0);
      Bh[bcc0 + 0][bk0] = b0.x;  Bh[bcc0 + 1][bk0] = b0.y;
      Bh[bcc0 + 2][bk0] = b0.z;  Bh[bcc0 + 3][bk0] = b0.w;
      ushort4 b1 = pack4((const float*)&wr1);
      Bh[bcc1 + 0][bk1] = b1.x;  Bh[bcc1 + 1][bk1] = b1.y;
      Bh[bcc1 + 2][bk1] = b1.z;  Bh[bcc1 + 3][bk1] = b1.w;
    }
    __syncthreads();

    if (s < 7) {                          // T14: issue next-step loads early
      int sn = (s + 1) * 32;
      xr0 = *(const float4*)&x[(size_t)(t0 + arow0) * F_ + sn + akc0];
      xr1 = *(const float4*)&x[(size_t)(t0 + arow1) * F_ + sn + akc1];
      wr0 = *(const float4*)&Wb[(size_t)(sn + bk0) * HQK + cOff + bcc0];
      wr1 = *(const float4*)&Wb[(size_t)(sn + bk1) * HQK + cOff + bcc1];
    }

    ABFrag a_h, a_l;
    a_h.h[0] = *(const ushort4*)&Ah[w * 16 + lr][lk];
    a_h.h[1] = *(const ushort4*)&Ah[w * 16 + lr][16 + lk];
    a_l.h[0] = *(const ushort4*)&Al[w * 16 + lr][lk];
    a_l.h[1] = *(const ushort4*)&Al[w * 16 + lr][16 + lk];
#pragma unroll
    for (int n = 0; n < 4; ++n) {
      ABFrag b_h;
      b_h.h[0] = *(const ushort4*)&Bh[n * 16 + lr][lk];
      b_h.h[1] = *(const ushort4*)&Bh[n * 16 + lr][16 + lk];
      acc[n] = __builtin_amdgcn_mfma_f32_16x16x32_bf16(a_h.v, b_h.v, acc[n], 0, 0, 0);
      acc[n] = __builtin_amdgcn_mfma_f32_16x16x32_bf16(a_l.v, b_h.v, acc[n], 0, 0, 0);
    }
  }

  if (c0 < HQK) {                         // q region -> f32
#pragma unroll
    for (int n = 0; n < 4; ++n)
#pragma unroll
      for (int i = 0; i < 4; ++i)
        qf[(size_t)(t0 + w * 16 + lk + i) * HQK + c0 + n * 16 + lr] =
            acc[n][i];
  } else {                                // k|v region -> bf16
    const int cb0 = c0 - HQK;
#pragma unroll
    for (int n = 0; n < 4; ++n)
#pragma unroll
      for (int i = 0; i < 4; ++i)
        kvb[(size_t)(t0 + w * 16 + lk + i) * KV2 + cb0 + n * 16 + lr] =
            f2bf(acc[n][i]);
  }
}

// ---------------------------------------------------------------------------
// K2+K3 fused (R14/R17 exact: 512 thr, wave = token, depth-4 ring, hi-only
// B, bf16 kv + z end-to-end, scalar pair-term with wp_s[c*H+h]).
// ---------------------------------------------------------------------------
__global__ __launch_bounds__(512) void attn_out_kernel(
    const float* __restrict__ R, const float* __restrict__ tvec,
    const float* __restrict__ pCB, const ushort* __restrict__ z_d,
    const int*   __restrict__ neighbors,
    const float* __restrict__ Wpair, const float* __restrict__ spatial_coef,
    const float* __restrict__ qf, const ushort* __restrict__ kvb,
    const ushort* __restrict__ wo,
    const float* __restrict__ b_out, const float* __restrict__ x,
    const float* __restrict__ ln_g, const float* __restrict__ ln_b,
    float* __restrict__ out) {
  const int tid   = threadIdx.x;          // 0..511
  const int t0    = blockIdx.x * 8;
  const int bbase = t0 & ~(L_ - 1);

  __shared__ float  q_s[8][HQK];
  __shared__ ushort z_s[8][M_][36];       // bf16 z tile (18.4 KB)
  __shared__ float  alpha_s[8][M_][13];
  __shared__ float  p_s[8][M_][4];
  __shared__ float  wp_s[C_ * H_];
  __shared__ float  gam_s[H_];
  __shared__ float  geo_s[8][16];
  __shared__ int    nb_s[8][M_];
  __shared__ float  aggr_s[8][H_][4];
  __shared__ ushort A2[8][A2S];           // packed feat {h4,l4}, 21.8 KB
  __shared__ float  part[16][8][2];
  __shared__ float  mu_s[16], rs_s[16];

  // ---- staging (cross-wave, barrier after) ----
  if (tid < 256) {
    int t = tid >> 5, m = tid & 31;
    nb_s[t][m] = neighbors[(t0 + t) * M_ + m];
  } else if (tid - 256 < H_) {
    gam_s[tid - 256] = log1pf(expf(spatial_coef[tid - 256]));
  }
  if (tid < C_ * H_) wp_s[tid] = Wpair[tid];
  if (tid < 96) {                         // zero 12 pad cols per token
    int t = tid / 12, c = FEAT + tid % 12;
    A2[t][(c >> 2) * 8 + (c & 3)]     = 0;
    A2[t][(c >> 2) * 8 + (c & 3) + 4] = 0;
  }
  if (tid < 384) {
    int t = tid / 48, r = tid % 48;
    *(float4*)&q_s[t][r * 4] =
        *(const float4*)&qf[(size_t)(t0 + t) * HQK + r * 4];
  }
  if (tid >= 384 && tid < 504) {
    int j = tid - 384, t = j / 15, w = j % 15;
    geo_s[t][w] = (w < 3) ? pCB[(t0 + t) * 3 + w]
                : (w < 6) ? tvec[(t0 + t) * 3 + (w - 3)]
                          : R[(t0 + t) * 9 + (w - 6)];
  }
  for (int i = tid; i < 2048; i += 512) {
    int t = i >> 8, r = i & 255, m = r >> 3, cq = r & 7;
    ushort4 v = *(const ushort4*)&z_d[((size_t)(t0 + t) * M_ + m) * C_ + cq * 4];
    *(ushort4*)&z_s[t][m][cq * 4] = v;
  }
  for (int i = tid; i < 8 * M_ * 3; i += 512) {
    int t = i / 96, r = i % 96, m = r / 3, ii = r % 3;
    int nb = neighbors[(t0 + t) * M_ + m];
    p_s[t][m][ii] = pCB[(bbase + nb) * 3 + ii];
  }
  __syncthreads();

  const int wv = tid >> 6;                // wave id == token index t
  const int l  = tid & 63;

  // ---- logits + softmax (wave-local; lane = (hgrp, m)) ----
  {
    const int t  = wv;
    const int m  = l & 31;
    const int hb = (l >> 5) * 6;         // head base: 0 or 6
    const int nb = nb_s[t][m];
    float lg[6];
#pragma unroll
    for (int h = 0; h < 6; ++h) lg[h] = 0.f;
#pragma unroll
    for (int c = 0; c < C_; ++c) {
      float zv = bf2f(z_s[t][m][c]);
#pragma unroll
      for (int h = 0; h < 6; ++h) lg[h] += zv * wp_s[c * H_ + hb + h];
    }
    union U8 { u16x8 v; ushort e[8]; };
    const ushort* kr = kvb + (size_t)(bbase + nb) * KV2;   // k at cols 0..191
#pragma unroll
    for (int h = 0; h < 6; ++h) {
      const int hh = hb + h;
      U8 ka, kb2;
      ka.v  = *(const u16x8*)&kr[hh * 16];
      kb2.v = *(const u16x8*)&kr[hh * 16 + 8];
      const float4* q4 = (const float4*)&q_s[t][hh * 16];
      float4 qa = q4[0], qb = q4[1], qc = q4[2], qd = q4[3];
      float nd = bf2f(ka.e[0]) * qa.x + bf2f(ka.e[1]) * qa.y
               + bf2f(ka.e[2]) * qa.z + bf2f(ka.e[3]) * qa.w
               + bf2f(ka.e[4]) * qb.x + bf2f(ka.e[5]) * qb.y
               + bf2f(ka.e[6]) * qb.z + bf2f(ka.e[7]) * qb.w
               + bf2f(kb2.e[0]) * qc.x + bf2f(kb2.e[1]) * qc.y
               + bf2f(kb2.e[2]) * qc.z + bf2f(kb2.e[3]) * qc.w
               + bf2f(kb2.e[4]) * qd.x + bf2f(kb2.e[5]) * qd.y
               + bf2f(kb2.e[6]) * qd.z + bf2f(kb2.e[7]) * qd.w;
      lg[h] += nd;
    }
    float dx = geo_s[t][0] - p_s[t][m][0];
    float dy = geo_s[t][1] - p_s[t][m][1];
    float dz = geo_s[t][2] - p_s[t][m][2];
    float d2 = dx * dx + dy * dy + dz * dz;
#pragma unroll
    for (int h = 0; h < 6; ++h)
      lg[h] = (lg[h] - d2 * gam_s[hb + h] * BETA_COEF) * LOGIT_SCALE;
#pragma unroll
    for (int h = 0; h < 6; ++h) {
      float mx = lg[h];
#pragma unroll
      for (int o = 16; o; o >>= 1) mx = fmaxf(mx, __shfl_xor(mx, o));
      float p = expf(lg[h] - mx);
      float s = p;
#pragma unroll
      for (int o = 16; o; o >>= 1) s += __shfl_xor(s, o);
      alpha_s[t][m][hb + h] = p / s;
    }
  }
  wave_sync();                            // alpha visible within wave

  // ---- feat_p2n -> A2 cols [0,384) (wave-local; z read ushort4) ----
  {
    const int t = wv;
    const int hp = l >> 3, cq = l & 7;
    if (hp < 6) {
      float acc0[4] = {0, 0, 0, 0}, acc1[4] = {0, 0, 0, 0};
#pragma unroll
      for (int m = 0; m < M_; ++m) {
        float a0 = alpha_s[t][m][hp * 2];
        float a1 = alpha_s[t][m][hp * 2 + 1];
        ushort4 zz = *(const ushort4*)&z_s[t][m][cq * 4];
        float z0 = bf2f(zz.x), z1 = bf2f(zz.y);
        float z2 = bf2f(zz.z), z3 = bf2f(zz.w);
        acc0[0] += a0 * z0; acc0[1] += a0 * z1;
        acc0[2] += a0 * z2; acc0[3] += a0 * z3;
        acc1[0] += a1 * z0; acc1[1] += a1 * z1;
        acc1[2] += a1 * z2; acc1[3] += a1 * z3;
      }
      ushort4 h4, l4;
      int c = (hp * 2) * C_ + cq * 4;
      split4(acc0, h4, l4);
      *(ushort4*)&A2[t][c * 2]     = h4;
      *(ushort4*)&A2[t][c * 2 + 4] = l4;
      c = (hp * 2 + 1) * C_ + cq * 4;
      split4(acc1, h4, l4);
      *(ushort4*)&A2[t][c * 2]     = h4;
      *(ushort4*)&A2[t][c * 2 + 4] = l4;
    }
  }
  // ---- feat_node -> A2 cols [384,576) (wave-local; v read bf16) ----
  {
    const int t = wv;
    const int h = l >> 2, dq = l & 3;
    if (h < 12) {
      float acc[4] = {0, 0, 0, 0};
#pragma unroll
      for (int m = 0; m < M_; ++m) {
        float a = alpha_s[t][m][h];
        const ushort* vr = kvb + (size_t)(bbase + nb_s[t][m]) * KV2 + HQK;
        ushort4 v4 = *(const ushort4*)&vr[h * QK_ + dq * 4];
        acc[0] += a * bf2f(v4.x); acc[1] += a * bf2f(v4.y);
        acc[2] += a * bf2f(v4.z); acc[3] += a * bf2f(v4.w);
      }
      ushort4 h4, l4;
      split4(acc, h4, l4);
      int c = 384 + h * QK_ + dq * 4;
      *(ushort4*)&A2[t][c * 2]     = h4;
      *(ushort4*)&A2[t][c * 2 + 4] = l4;
    }
  }
  // ---- aggr (wave-local: lanes 0..35) ----
  if (l < 36) {
    const int t = wv;
    int h = l / 3, ii = l % 3;
    float f = 0.f;
#pragma unroll
    for (int m = 0; m < M_; ++m) f += alpha_s[t][m][h] * p_s[t][m][ii];
    aggr_s[t][h][ii] = f;
  }
  wave_sync();                            // aggr visible within wave

  // ---- spatial feats -> A2 cols [576,660) (wave-local: lanes 0..11) ----
  if (l < 12) {
    const int t = wv;
    const int h = l;
    float a0 = aggr_s[t][h][0] - geo_s[t][3];
    float a1 = aggr_s[t][h][1] - geo_s[t][4];
    float a2 = aggr_s[t][h][2] - geo_s[t][5];
    float lx = geo_s[t][6] * a0 + geo_s[t][9]  * a1 + geo_s[t][12] * a2;
    float ly = geo_s[t][7] * a0 + geo_s[t][10] * a1 + geo_s[t][13] * a2;
    float lz = geo_s[t][8] * a0 + geo_s[t][11] * a1 + geo_s[t][14] * a2;
    float dist = sqrtf(lx * lx + ly * ly + lz * lz);
    float inv  = 1.f / (dist + EPS_DIR);
    float vals[7] = {lx, ly, lz, dist, lx * inv, ly * inv, lz * inv};
    int   cols[7] = {576 + 3 * h, 577 + 3 * h, 578 + 3 * h, 612 + h,
                     624 + 3 * h, 625 + 3 * h, 626 + 3 * h};
#pragma unroll
    for (int j = 0; j < 7; ++j) {
      int c = cols[j];
      ushort hh = f2bf(vals[j]);
      A2[t][(c >> 2) * 8 + (c & 3)]     = hh;
      A2[t][(c >> 2) * 8 + (c & 3) + 4] = f2bf(vals[j] - bf2f(hh));
    }
  }

  // ---- out GEMM: 8 tok (dual-row hi/lo) x 256 col, K = 672, hi-only B ----
  const int w  = wv;
  const int lr = l & 15, lk = (l >> 4) * 4;
  const int atok = lr & 7;                // A row -> token
  const int asel = (lr >> 3) * 4;         // 0 = hi quad, 4 = lo quad
  const int col0 = (w * 2 + 0) * 16 + lr;
  const int col1 = (w * 2 + 1) * 16 + lr;
  // frag-permuted wo: lane's 16B at col*FPAD + s*32 + lk*2 holds
  // {k=s*32+lk..+3, k=s*32+16+lk..+3} -- exactly h[0],h[1].
  const ushort* wo0 = wo + (size_t)col0 * FPAD + lk * 2;
  const ushort* wo1 = wo + (size_t)col1 * FPAD + lk * 2;

  union ABFrag { bf16x8 v; ushort4 h[2]; };
  union B8 { u16x8 v; ushort4 q[2]; };

  B8 pb[4][2];                            // [buf][n] depth-4 ring

#define PREF_B(sstep, buf) do {                                          \
    pb[buf][0].v = *(const u16x8*)&wo0[(sstep) * 32];                    \
    pb[buf][1].v = *(const u16x8*)&wo1[(sstep) * 32];                    \
  } while (0)

  PREF_B(0, 0);                           // overlap with spatial phase +
  PREF_B(1, 1);                           // the barrier below
  PREF_B(2, 2);
  PREF_B(3, 3);
  __syncthreads();                        // feat LDS ready (cross-wave)

  f32x4 acc[2];
  acc[0] = (f32x4){0.f, 0.f, 0.f, 0.f};
  acc[1] = (f32x4){0.f, 0.f, 0.f, 0.f};

#pragma unroll
  for (int s = 0; s < 21; ++s) {
    const int cb = s & 3;
    // A frag, proven k-split: k = {s*32+lk..+3} u {s*32+16+lk..+3};
    // asel picks hi (rows 0..7) or lo (rows 8..15) quad of the packed pair.
    const int k0 = s * 32 + lk;
    ABFrag a;
    a.h[0] = *(const ushort4*)&A2[atok][k0 * 2 + asel];
    a.h[1] = *(const ushort4*)&A2[atok][(k0 + 16) * 2 + asel];
    ABFrag b0, b1;
    b0.h[0] = pb[cb][0].q[0];  b0.h[1] = pb[cb][0].q[1];
    b1.h[0] = pb[cb][1].q[0];  b1.h[1] = pb[cb][1].q[1];
    if (s < 17) PREF_B(s + 4, cb);        // refill consumed ring slot
    acc[0] = __builtin_amdgcn_mfma_f32_16x16x32_bf16(a.v, b0.v, acc[0], 0, 0, 0);
    acc[1] = __builtin_amdgcn_mfma_f32_16x16x32_bf16(a.v, b1.v, acc[1], 0, 0, 0);
  }
#undef PREF_B

  // cross-half combine: C row r (r<8) = acc[r] + acc[r+8] = (hi+lo)*bh;
  // l^32 flips the C row by 8 (col = l&15 preserved); both halves identical.
#pragma unroll
  for (int n = 0; n < 2; ++n)
#pragma unroll
    for (int i = 0; i < 4; ++i)
      acc[n][i] += __shfl_xor(acc[n][i], 32);

  // ---- epilogue: h = acc + b_out + x; block-local LN over 256 cols ----
  float hv[4][2];                          // [row i][col tile n]
#pragma unroll
  for (int i = 0; i < 4; ++i) {
    const int row = (lk + i) & 7;          // rows 8..15 duplicate 0..7
#pragma unroll
    for (int n = 0; n < 2; ++n) {
      const int col = (w * 2 + n) * 16 + lr;
      hv[i][n] = acc[n][i] + b_out[col] + x[(size_t)(t0 + row) * F_ + col];
    }
  }
#pragma unroll
  for (int i = 0; i < 4; ++i) {
    float s  = hv[i][0] + hv[i][1];
    float sq = hv[i][0] * hv[i][0] + hv[i][1] * hv[i][1];
#pragma unroll
    for (int o = 1; o < 16; o <<= 1) {     // reduce within 16-lane group
      s  += __shfl_xor(s, o);
      sq += __shfl_xor(sq, o);
    }
    if (lr == 0) {
      part[lk + i][w][0] = s;              // raw row index: unique writer
      part[lk + i][w][1] = sq;
    }
  }
  __syncthreads();
  if (tid < 16) {
    float s = 0.f, sq = 0.f;
#pragma unroll
    for (int ww = 0; ww < 8; ++ww) {
      s  += part[tid][ww][0];
      sq += part[tid][ww][1];
    }
    float mu = s * (1.f / F_);
    mu_s[tid] = mu;
    rs_s[tid] = rsqrtf(sq * (1.f / F_) - mu * mu + LN_EPS);
  }
  __syncthreads();

  if (lk < 8) {                            // rows 0..7 only (8..15 dup)
#pragma unroll
    for (int n = 0; n < 2; ++n) {
      const int col = (w * 2 + n) * 16 + lr;
      const float g = ln_g[col], be = ln_b[col];
#pragma unroll
      for (int i = 0; i < 4; ++i) {
        const int row = lk + i;
        out[(size_t)(t0 + row) * F_ + col] =
            (hv[i][n] - mu_s[row]) * rs_s[row] * g + be;
      }
    }
  }
}

// ---------------------------------------------------------------------------
extern "C" void kernel_launch(void* const* d_in, const int* in_sizes, int n_in,
                              void* d_out, int out_size, void* d_ws,
                              size_t ws_size, hipStream_t stream) {
  const float* R     = (const float*)d_in[0];
  const float* t     = (const float*)d_in[1];
  const float* pCB   = (const float*)d_in[2];
  const float* x     = (const float*)d_in[3];
  const float* z     = (const float*)d_in[4];
  const int*   nb    = (const int*)d_in[6];
  const float* Wq    = (const float*)d_in[7];
  const float* Wk    = (const float*)d_in[8];
  const float* Wv    = (const float*)d_in[9];
  const float* Wpair = (const float*)d_in[10];
  const float* sc    = (const float*)d_in[11];
  const float* Wout  = (const float*)d_in[12];
  const float* bout  = (const float*)d_in[13];
  const float* g     = (const float*)d_in[14];
  const float* be    = (const float*)d_in[15];
  float* out  = (float*)d_out;

  float*  qf   = (float*)d_ws;                     // 2048*192 f32
  ushort* kvb  = (ushort*)(qf + (size_t)NTOK * HQK);   // 2048*384 bf16
  ushort* z_d  = kvb + (size_t)NTOK * KV2;             // 2048*32*32 bf16
  ushort* wo   = z_d + (size_t)NTOK * M_ * C_;         // 256*672 hi-only

  qkv_prep_kernel<<<832, 256, 0, stream>>>(x, Wq, Wk, Wv, Wout, z, nb,
                                           qf, kvb, wo, z_d);
  attn_out_kernel<<<NTOK / 8, 512, 0, stream>>>(R, t, pCB, z_d, nb, Wpair,
                                                sc, qf, kvb, wo, bout, x,
                                                g, be, out);
}